// Round 7
// baseline (18876.944 us; speedup 1.0000x reference)
//
#include <hip/hip_runtime.h>
#include <hip/hip_bf16.h>
#include <hip/hip_fp16.h>
#include <hip/hip_cooperative_groups.h>

namespace cg = cooperative_groups;

#define N_RES   4096
#define MAXD    4608
#define IN_DIM  1024
#define T_STEPS 128
#define B_SZ    128
#define KPRE    3072   // 3 * 1024 (hi*hi | hi*lo | lo*hi)

typedef __attribute__((ext_vector_type(8))) short bf16x8;
typedef __attribute__((ext_vector_type(4))) float f32x4;

__device__ __forceinline__ short f2bf(float x) {
  union { float f; unsigned u; } v; v.f = x;
  unsigned r = v.u + 0x7fffu + ((v.u >> 16) & 1u);
  return (short)(r >> 16);
}
__device__ __forceinline__ float bf2f(short b) {
  union { float f; unsigned u; } v; v.u = ((unsigned)(unsigned short)b) << 16;
  return v.f;
}

__device__ __forceinline__ void gload16(const void* g, void* l) {
  __builtin_amdgcn_global_load_lds(
      (const __attribute__((address_space(1))) void*)g,
      (__attribute__((address_space(3))) void*)l,
      16, 0, 0);
}

// ---------------- zero ONLY the padding columns [4096,4608) ----------------
__global__ void k_zero_pad(float* __restrict__ out) {
  int row = blockIdx.x;            // 16384 rows (T*B)
  int t = threadIdx.x;             // 128 threads * float4 = 512 cols
  *(float4*)(out + (size_t)row * MAXD + N_RES + t * 4) = float4{0.f, 0.f, 0.f, 0.f};
}

// ---------------- init state from state0 ----------------
__global__ void k_init_state(const float* __restrict__ s0,
                             float* __restrict__ sF, short* __restrict__ sB) {
  int i = blockIdx.x * 256 + threadIdx.x;   // 128*4096 total
  int m = i >> 12, n = i & 4095;
  float v = s0[m * MAXD + n];
  sF[i] = v;
  sB[i] = f2bf(v);
}

// ---------------- transpose W_res -> bf16 [n][k] ----------------
__global__ void k_wres_t(const float* __restrict__ W, short* __restrict__ bt) {
  __shared__ float tile[64][65];
  int k0 = blockIdx.y * 64, n0 = blockIdx.x * 64;
  int tx = threadIdx.x & 63, ty = threadIdx.x >> 6;   // 256 thr
  #pragma unroll
  for (int r = 0; r < 64; r += 4)
    tile[r + ty][tx] = W[(long)(k0 + r + ty) * N_RES + n0 + tx];
  __syncthreads();
  #pragma unroll
  for (int r = 0; r < 64; r += 4)
    bt[(long)(n0 + r + ty) * N_RES + k0 + tx] = f2bf(tile[tx][r + ty]);
}

// ---------------- build B2 = [Whi | Wlo | Whi] rows of [W_in;W_gate] ----------------
__global__ void k_build_b2(const float* __restrict__ Win,
                           const float* __restrict__ Wg, short* __restrict__ B2) {
  int r = blockIdx.x;   // 16384 rows
  const float* src = (r < N_RES) ? (Win + (long)r * IN_DIM)
                                 : (Wg + (long)(r - N_RES) * IN_DIM);
  short* dst = B2 + (long)r * KPRE;
  for (int c = threadIdx.x; c < IN_DIM; c += 256) {
    float x = src[c];
    short h = f2bf(x);
    short l = f2bf(x - bf2f(h));
    dst[c] = h; dst[IN_DIM + c] = l; dst[2 * IN_DIM + c] = h;
  }
}

// ---------------- build A2 chunk = [Xhi | Xhi | Xlo] ----------------
__global__ void k_build_a2(const float* __restrict__ x, short* __restrict__ A2, int t0) {
  int r = blockIdx.x;   // Tc*128 rows
  const float* src = x + (long)(t0 * B_SZ + r) * IN_DIM;
  short* dst = A2 + (long)r * KPRE;
  for (int c = threadIdx.x; c < IN_DIM; c += 256) {
    float v = src[c];
    short h = f2bf(v);
    short l = f2bf(v - bf2f(h));
    dst[c] = h; dst[IN_DIM + c] = h; dst[2 * IN_DIM + c] = l;
  }
}

// ---------------- precompute GEMM: C = A2 @ B2^T  (256x256 8-phase) ----------------
__global__ __launch_bounds__(512, 2) void k_gemm_pre(
    const short* __restrict__ A2, const short* __restrict__ B2,
    _Float16* __restrict__ ip, _Float16* __restrict__ gates, int Mrows) {
  __shared__ short lA[2][2][128 * 64];
  __shared__ short lB[2][2][128 * 64];
  int tid = threadIdx.x, lane = tid & 63, wid = tid >> 6;
  int wr = wid >> 2, wc = wid & 3;

  // bijective XCD swizzle (m204), mt-major chunks per XCD
  int nwg = gridDim.x, orig = blockIdx.x;
  int qx = nwg >> 3, rx = nwg & 7, xcd = orig & 7;
  int wgid = (xcd < rx ? xcd * (qx + 1) : rx * (qx + 1) + (xcd - rx) * qx) + (orig >> 3);
  int mt = wgid >> 6, nt = wgid & 63;
  long m0 = (long)mt * 256, n0 = (long)nt * 256;
  long mclamp = Mrows - 1;

  int c0 = tid, c1 = 512 + tid;
  int r0 = c0 >> 3, r1 = c1 >> 3;
  int cc0 = ((c0 & 7) ^ (r0 & 7)) * 8, cc1 = ((c1 & 7) ^ (r1 & 7)) * 8;

  const short *pA00, *pA01, *pA10, *pA11, *pB00, *pB01, *pB10, *pB11;
  {
    long a00 = m0 + r0;       if (a00 > mclamp) a00 = mclamp;
    long a01 = m0 + r1;       if (a01 > mclamp) a01 = mclamp;
    long a10 = m0 + 128 + r0; if (a10 > mclamp) a10 = mclamp;
    long a11 = m0 + 128 + r1; if (a11 > mclamp) a11 = mclamp;
    pA00 = A2 + a00 * KPRE + cc0;  pA01 = A2 + a01 * KPRE + cc1;
    pA10 = A2 + a10 * KPRE + cc0;  pA11 = A2 + a11 * KPRE + cc1;
    pB00 = B2 + (n0 + r0) * KPRE + cc0;        pB01 = B2 + (n0 + r1) * KPRE + cc1;
    pB10 = B2 + (n0 + 128 + r0) * KPRE + cc0;  pB11 = B2 + (n0 + 128 + r1) * KPRE + cc1;
  }

  #define STG_A0(kt, b) { gload16(pA00 + (kt)*64, &lA[b][0][c0*8]); gload16(pA01 + (kt)*64, &lA[b][0][c1*8]); }
  #define STG_A1(kt, b) { gload16(pA10 + (kt)*64, &lA[b][1][c0*8]); gload16(pA11 + (kt)*64, &lA[b][1][c1*8]); }
  #define STG_B0(kt, b) { gload16(pB00 + (kt)*64, &lB[b][0][c0*8]); gload16(pB01 + (kt)*64, &lB[b][0][c1*8]); }
  #define STG_B1(kt, b) { gload16(pB10 + (kt)*64, &lB[b][1][c0*8]); gload16(pB11 + (kt)*64, &lB[b][1][c1*8]); }

  int lm = lane & 15;
  int colS0 = ((lane >> 4) * 8) ^ ((lane & 7) << 3);
  int colS1 = (32 + (lane >> 4) * 8) ^ ((lane & 7) << 3);
  int arow[4], brow[2];
  #pragma unroll
  for (int i = 0; i < 4; ++i) arow[i] = (wr * 64 + i * 16 + lm) * 64;
  #pragma unroll
  for (int j = 0; j < 2; ++j) brow[j] = (wc * 32 + j * 16 + lm) * 64;

  bf16x8 aF[4][2], bF[2][2];
  f32x4 acc[2][4][4] = {};

  #define RD_A(qm, b) { _Pragma("unroll") for (int i = 0; i < 4; ++i) {        \
      aF[i][0] = *(const bf16x8*)&lA[b][qm][arow[i] + colS0];                  \
      aF[i][1] = *(const bf16x8*)&lA[b][qm][arow[i] + colS1]; } }
  #define RD_B(qn, b) { _Pragma("unroll") for (int j = 0; j < 2; ++j) {        \
      bF[j][0] = *(const bf16x8*)&lB[b][qn][brow[j] + colS0];                  \
      bF[j][1] = *(const bf16x8*)&lB[b][qn][brow[j] + colS1]; } }
  #define MM(qm, qn) { __builtin_amdgcn_s_setprio(1);                          \
      _Pragma("unroll") for (int i = 0; i < 4; ++i)                            \
      _Pragma("unroll") for (int j = 0; j < 2; ++j) {                          \
        acc[qm][i][(qn)*2+j] = __builtin_amdgcn_mfma_f32_16x16x32_bf16(        \
            aF[i][0], bF[j][0], acc[qm][i][(qn)*2+j], 0, 0, 0);                \
        acc[qm][i][(qn)*2+j] = __builtin_amdgcn_mfma_f32_16x16x32_bf16(        \
            aF[i][1], bF[j][1], acc[qm][i][(qn)*2+j], 0, 0, 0); }              \
      __builtin_amdgcn_s_setprio(0); }

  STG_A0(0, 0); STG_B0(0, 0); STG_B1(0, 0); STG_A1(0, 0);

  const int nk = KPRE / 64;   // 48
  for (int kt = 0; kt < nk; ++kt) {
    int buf = kt & 1, nbuf = buf ^ 1;
    int ktn = (kt + 1 < nk) ? kt + 1 : kt;
    asm volatile("s_waitcnt vmcnt(4)\n\ts_barrier" ::: "memory");
    RD_A(0, buf); RD_B(0, buf);
    STG_A0(ktn, nbuf);
    MM(0, 0);
    asm volatile("s_barrier" ::: "memory");
    asm volatile("s_waitcnt vmcnt(4)\n\ts_barrier" ::: "memory");
    RD_B(1, buf);
    STG_B0(ktn, nbuf);
    MM(0, 1);
    asm volatile("s_barrier" ::: "memory");
    asm volatile("s_waitcnt vmcnt(4)\n\ts_barrier" ::: "memory");
    RD_A(1, buf); RD_B(0, buf);
    STG_B1(ktn, nbuf);
    MM(1, 0);
    asm volatile("s_barrier" ::: "memory");
    RD_B(1, buf);
    STG_A1(ktn, nbuf);
    MM(1, 1);
    asm volatile("s_barrier" ::: "memory");
  }
  #undef STG_A0
  #undef STG_A1
  #undef STG_B0
  #undef STG_B1
  #undef RD_A
  #undef RD_B
  #undef MM

  #pragma unroll
  for (int qm = 0; qm < 2; ++qm)
    #pragma unroll
    for (int i = 0; i < 4; ++i)
      #pragma unroll
      for (int qn = 0; qn < 2; ++qn)
        #pragma unroll
        for (int j = 0; j < 2; ++j)
          #pragma unroll
          for (int q = 0; q < 4; ++q) {
            long m = m0 + qm * 128 + wr * 64 + i * 16 + (lane >> 4) * 4 + q;
            long n = n0 + qn * 128 + wc * 32 + j * 16 + lm;
            if (m >= Mrows) continue;
            float v = acc[qm][i][qn * 2 + j][q];
            if (n < N_RES) {
              ip[m * N_RES + n] = (_Float16)v;
            } else {
              gates[m * 12288 + (n - N_RES)] = (_Float16)(1.f / (1.f + __expf(-v)));
            }
          }
}

// ---------------- persistent cooperative kernel: ALL Tc steps ----------------
// 256 blocks x 512 thr (1/CU). Per step: R6's 3-buffer counted pipeline +
// register-resident fp32 state + fused epilogue, then threadfence + grid.sync.
__global__ __launch_bounds__(512) void k_steps(
    short* __restrict__ sB0, short* __restrict__ sB1,
    const short* __restrict__ Bt,
    const _Float16* __restrict__ ipb,   // [Tc][128][4096]
    const _Float16* __restrict__ gtb,   // [Tc][128][12288]
    const float* __restrict__ state0,   // [128][4608]
    float* __restrict__ sF,             // fp32 state spill [128][4096]
    float* __restrict__ out,            // full output base
    int t0, int Tc) {
  cg::grid_group grid = cg::this_grid();
  __shared__ short lA[3][64 * 128];     // 3 x 16 KiB
  __shared__ short lB[3][32 * 128];     // 3 x 8 KiB
  int tid = threadIdx.x, lane = tid & 63, wid = tid >> 6;   // 8 waves
  int wm = wid >> 1, wn = wid & 1;

  // XCD-aware mapping: blockIdx%8 = XCD; n-slice pinned per XCD.
  int b = blockIdx.x;                   // 0..255
  int slot = b >> 3;                    // 0..31
  int n_tile = (b & 7) * 16 + (slot & 15);
  int m_half = slot >> 4;
  int n0 = n_tile * 32;
  int m0 = m_half * 64;

  // staging offsets (state buffer alternates; B fixed)
  const int cA0 = tid, cA1 = 512 + tid, cB0 = tid;
  const size_t offA0 = (size_t)(m0 + (cA0 >> 4)) * N_RES + (((cA0 & 15) ^ ((cA0 >> 4) & 7)) * 8);
  const size_t offA1 = (size_t)(m0 + (cA1 >> 4)) * N_RES + (((cA1 & 15) ^ ((cA1 >> 4) & 7)) * 8);
  const short* pB0 = Bt + (size_t)(n0 + (cB0 >> 4)) * N_RES + (((cB0 & 15) ^ ((cB0 >> 4) & 7)) * 8);

  // this thread's static output coords
  int mq = m0 + wm * 16 + (lane >> 4) * 4;    // rows mq..mq+3
  int nn = n0 + wn * 16 + (lane & 15);        // col

  // fp32 state in registers
  float stF[4];
  if (t0 == 0) {
    #pragma unroll
    for (int q = 0; q < 4; ++q) stF[q] = state0[(size_t)(mq + q) * MAXD + nn];
  } else {
    #pragma unroll
    for (int q = 0; q < 4; ++q) stF[q] = sF[(size_t)(mq + q) * N_RES + nn];
  }

  #define STAGE(Ab, kt, bi)                              \
    {                                                    \
      int k0s = (kt) * 128;                              \
      gload16(Ab + offA0 + k0s, &lA[bi][cA0 * 8]);       \
      gload16(Ab + offA1 + k0s, &lA[bi][cA1 * 8]);       \
      gload16(pB0 + k0s, &lB[bi][cB0 * 8]);              \
    }

  #define COMPUTE(bi)                                                          \
    { _Pragma("unroll")                                                        \
      for (int kk = 0; kk < 128; kk += 32) {                                   \
        int colS = (kk + (lane >> 4) * 8) ^ ((lane & 7) << 3);                 \
        bf16x8 aF = *(const bf16x8*)&lA[bi][(wm * 16 + (lane & 15)) * 128 + colS]; \
        bf16x8 bF = *(const bf16x8*)&lB[bi][(wn * 16 + (lane & 15)) * 128 + colS]; \
        acc = __builtin_amdgcn_mfma_f32_16x16x32_bf16(aF, bF, acc, 0, 0, 0);   \
      } }

  for (int tl = 0; tl < Tc; ++tl) {
    int t = t0 + tl;
    const short* Ab = (t & 1) ? sB1 : sB0;
    short*       Aw = (t & 1) ? sB0 : sB1;
    const _Float16* ipt = ipb + (size_t)tl * B_SZ * N_RES;
    const _Float16* gtt = gtb + (size_t)tl * B_SZ * 12288;
    float* outT = out + (size_t)t * B_SZ * MAXD;

    f32x4 acc = {};
    STAGE(Ab, 0, 0);
    STAGE(Ab, 1, 1);                   // 6 loads in flight

    int bi = 0, sb = 2;
    for (int kt = 0; kt < 31; ++kt) {
      asm volatile("s_waitcnt vmcnt(3)" ::: "memory");
      __builtin_amdgcn_s_barrier();
      if (kt < 30) STAGE(Ab, kt + 2, sb);
      COMPUTE(bi);
      ++bi; if (bi == 3) bi = 0;
      ++sb; if (sb == 3) sb = 0;
    }
    asm volatile("s_waitcnt vmcnt(0)" ::: "memory");
    __builtin_amdgcn_s_barrier();

    // epilogue operand loads issued before the last MFMA cluster (latency hidden)
    float ipv[4], igv[4], fgv[4], ogv[4];
    #pragma unroll
    for (int q = 0; q < 4; ++q) {
      ipv[q] = (float)ipt[(size_t)(mq + q) * N_RES + nn];
      const _Float16* grow = gtt + (size_t)(mq + q) * 12288 + nn;
      igv[q] = (float)grow[0];
      fgv[q] = (float)grow[4096];
      ogv[q] = (float)grow[8192];
    }

    COMPUTE(bi);                       // tile 31

    #pragma unroll
    for (int q = 0; q < 4; ++q) {
      float s = 0.9f * (fgv[q] * stF[q]) + 0.1f * tanhf(igv[q] * (ipv[q] + acc[q]));
      s = ogv[q] * s;
      if (s > 0.5f) s -= 0.5f;
      stF[q] = s;
      outT[(size_t)(mq + q) * MAXD + nn] = s;
      Aw[(size_t)(mq + q) * N_RES + nn] = f2bf(s);
    }

    __threadfence();                   // release: state writes visible device-wide
    grid.sync();
    __threadfence();                   // acquire: invalidate stale L2 for A reads
  }
  #undef STAGE
  #undef COMPUTE

  // spill fp32 state for next chunk (Tc<128 fallback)
  #pragma unroll
  for (int q = 0; q < 4; ++q) sF[(size_t)(mq + q) * N_RES + nn] = stF[q];
}

extern "C" void kernel_launch(void* const* d_in, const int* in_sizes, int n_in,
                              void* d_out, int out_size, void* d_ws, size_t ws_size,
                              hipStream_t stream) {
  const float* x      = (const float*)d_in[0];
  const float* state0 = (const float*)d_in[1];
  const float* W_res  = (const float*)d_in[2];
  const float* W_in   = (const float*)d_in[3];
  const float* W_gate = (const float*)d_in[4];
  float* out = (float*)d_out;
  char* ws = (char*)d_ws;

  size_t off = 0;
  short* WresBT = (short*)(ws + off); off += (size_t)N_RES * N_RES * 2;       // 33.6 MB
  short* B2     = (short*)(ws + off); off += (size_t)16384 * KPRE * 2;        // 100.7 MB
  float* sF     = (float*)(ws + off); off += (size_t)B_SZ * N_RES * 4;        // 2 MB
  short* sB0    = (short*)(ws + off); off += (size_t)B_SZ * N_RES * 2;        // 1 MB
  short* sB1    = (short*)(ws + off); off += (size_t)B_SZ * N_RES * 2;        // 1 MB
  size_t fixed = off;
  size_t per = (size_t)B_SZ * KPRE * 2 + (size_t)B_SZ * N_RES * 2 + (size_t)B_SZ * 12288 * 2;

  int Tc = T_STEPS;
  while (Tc > 1 && fixed + (size_t)Tc * per > ws_size) Tc >>= 1;

  short*     A2  = (short*)(ws + fixed);
  _Float16*  ipb = (_Float16*)(ws + fixed + (size_t)Tc * B_SZ * KPRE * 2);
  _Float16*  gtb = (_Float16*)(ws + fixed + (size_t)Tc * B_SZ * KPRE * 2
                               + (size_t)Tc * B_SZ * N_RES * 2);

  k_zero_pad<<<T_STEPS * B_SZ, 128, 0, stream>>>(out);
  k_init_state<<<(B_SZ * N_RES) / 256, 256, 0, stream>>>(state0, sF, sB0);
  k_wres_t<<<dim3(64, 64), 256, 0, stream>>>(W_res, WresBT);
  k_build_b2<<<16384, 256, 0, stream>>>(W_in, W_gate, B2);

  for (int t0 = 0; t0 < T_STEPS; t0 += Tc) {
    k_build_a2<<<Tc * B_SZ, 256, 0, stream>>>(x, A2, t0);
    int Mrows = Tc * B_SZ;
    int mtiles = (Mrows + 255) / 256;
    k_gemm_pre<<<mtiles * 64, 512, 0, stream>>>(A2, B2, ipb, gtb, Mrows);

    int t0v = t0, Tcv = Tc;
    void* kargs[] = { (void*)&sB0, (void*)&sB1, (void*)&WresBT,
                      (void*)&ipb, (void*)&gtb, (void*)&state0,
                      (void*)&sF, (void*)&out, (void*)&t0v, (void*)&Tcv };
    hipLaunchCooperativeKernel((void*)k_steps, dim3(256), dim3(512),
                               kargs, 0, stream);
  }
}

// Round 8
// 4055.546 us; speedup vs baseline: 4.6546x; 4.6546x over previous
//
#include <hip/hip_runtime.h>
#include <hip/hip_bf16.h>
#include <hip/hip_fp16.h>

#define N_RES   4096
#define MAXD    4608
#define IN_DIM  1024
#define T_STEPS 128
#define B_SZ    128
#define KPRE    3072   // 3 * 1024 (hi*hi | hi*lo | lo*hi)

typedef __attribute__((ext_vector_type(8))) short bf16x8;
typedef __attribute__((ext_vector_type(4))) float f32x4;

__device__ __forceinline__ short f2bf(float x) {
  union { float f; unsigned u; } v; v.f = x;
  unsigned r = v.u + 0x7fffu + ((v.u >> 16) & 1u);
  return (short)(r >> 16);
}
__device__ __forceinline__ float bf2f(short b) {
  union { float f; unsigned u; } v; v.u = ((unsigned)(unsigned short)b) << 16;
  return v.f;
}

__device__ __forceinline__ void gload16(const void* g, void* l) {
  __builtin_amdgcn_global_load_lds(
      (const __attribute__((address_space(1))) void*)g,
      (__attribute__((address_space(3))) void*)l,
      16, 0, 0);
}

// ---------------- zero ONLY the padding columns [4096,4608) ----------------
__global__ void k_zero_pad(float* __restrict__ out) {
  int row = blockIdx.x;            // 16384 rows (T*B)
  int t = threadIdx.x;             // 128 threads * float4 = 512 cols
  *(float4*)(out + (size_t)row * MAXD + N_RES + t * 4) = float4{0.f, 0.f, 0.f, 0.f};
}

// ---------------- init state from state0 ----------------
__global__ void k_init_state(const float* __restrict__ s0,
                             float* __restrict__ sF, short* __restrict__ sB) {
  int i = blockIdx.x * 256 + threadIdx.x;   // 128*4096 total
  int m = i >> 12, n = i & 4095;
  float v = s0[m * MAXD + n];
  sF[i] = v;
  sB[i] = f2bf(v);
}

// ---------------- transpose W_res -> bf16 [n][k] ----------------
__global__ void k_wres_t(const float* __restrict__ W, short* __restrict__ bt) {
  __shared__ float tile[64][65];
  int k0 = blockIdx.y * 64, n0 = blockIdx.x * 64;
  int tx = threadIdx.x & 63, ty = threadIdx.x >> 6;   // 256 thr
  #pragma unroll
  for (int r = 0; r < 64; r += 4)
    tile[r + ty][tx] = W[(long)(k0 + r + ty) * N_RES + n0 + tx];
  __syncthreads();
  #pragma unroll
  for (int r = 0; r < 64; r += 4)
    bt[(long)(n0 + r + ty) * N_RES + k0 + tx] = f2bf(tile[tx][r + ty]);
}

// ---------------- build B2 = [Whi | Wlo | Whi] rows of [W_in;W_gate] ----------------
__global__ void k_build_b2(const float* __restrict__ Win,
                           const float* __restrict__ Wg, short* __restrict__ B2) {
  int r = blockIdx.x;   // 16384 rows
  const float* src = (r < N_RES) ? (Win + (long)r * IN_DIM)
                                 : (Wg + (long)(r - N_RES) * IN_DIM);
  short* dst = B2 + (long)r * KPRE;
  for (int c = threadIdx.x; c < IN_DIM; c += 256) {
    float x = src[c];
    short h = f2bf(x);
    short l = f2bf(x - bf2f(h));
    dst[c] = h; dst[IN_DIM + c] = l; dst[2 * IN_DIM + c] = h;
  }
}

// ---------------- build A2 chunk = [Xhi | Xhi | Xlo] ----------------
__global__ void k_build_a2(const float* __restrict__ x, short* __restrict__ A2, int t0) {
  int r = blockIdx.x;   // Tc*128 rows
  const float* src = x + (long)(t0 * B_SZ + r) * IN_DIM;
  short* dst = A2 + (long)r * KPRE;
  for (int c = threadIdx.x; c < IN_DIM; c += 256) {
    float v = src[c];
    short h = f2bf(v);
    short l = f2bf(v - bf2f(h));
    dst[c] = h; dst[IN_DIM + c] = h; dst[2 * IN_DIM + c] = l;
  }
}

// ---------------- precompute GEMM: C = A2 @ B2^T  (256x256 8-phase, B-dedup) ----
// BM=BN=256, BK=64, 512 thr (8 waves 2Mx4N), per-wave 128x64 out.
// LDS: 2buf x 2half x 128x64 for A and B = 128 KiB. XOR-swizzled (both sides).
// B fragments for BOTH halves held in registers (bFh) -> each B half-tile is
// ds_read exactly once per K-tile (24 reads/wave/K-tile, was 32).
__global__ __launch_bounds__(512, 2) void k_gemm_pre(
    const short* __restrict__ A2, const short* __restrict__ B2,
    _Float16* __restrict__ ip, _Float16* __restrict__ gates, int Mrows) {
  __shared__ short lA[2][2][128 * 64];
  __shared__ short lB[2][2][128 * 64];
  int tid = threadIdx.x, lane = tid & 63, wid = tid >> 6;
  int wr = wid >> 2, wc = wid & 3;

  // bijective XCD swizzle (m204), mt-major chunks per XCD
  int nwg = gridDim.x, orig = blockIdx.x;
  int qx = nwg >> 3, rx = nwg & 7, xcd = orig & 7;
  int wgid = (xcd < rx ? xcd * (qx + 1) : rx * (qx + 1) + (xcd - rx) * qx) + (orig >> 3);
  int mt = wgid >> 6, nt = wgid & 63;
  long m0 = (long)mt * 256, n0 = (long)nt * 256;
  long mclamp = Mrows - 1;

  int c0 = tid, c1 = 512 + tid;
  int r0 = c0 >> 3, r1 = c1 >> 3;
  int cc0 = ((c0 & 7) ^ (r0 & 7)) * 8, cc1 = ((c1 & 7) ^ (r1 & 7)) * 8;

  const short *pA00, *pA01, *pA10, *pA11, *pB00, *pB01, *pB10, *pB11;
  {
    long a00 = m0 + r0;       if (a00 > mclamp) a00 = mclamp;
    long a01 = m0 + r1;       if (a01 > mclamp) a01 = mclamp;
    long a10 = m0 + 128 + r0; if (a10 > mclamp) a10 = mclamp;
    long a11 = m0 + 128 + r1; if (a11 > mclamp) a11 = mclamp;
    pA00 = A2 + a00 * KPRE + cc0;  pA01 = A2 + a01 * KPRE + cc1;
    pA10 = A2 + a10 * KPRE + cc0;  pA11 = A2 + a11 * KPRE + cc1;
    pB00 = B2 + (n0 + r0) * KPRE + cc0;        pB01 = B2 + (n0 + r1) * KPRE + cc1;
    pB10 = B2 + (n0 + 128 + r0) * KPRE + cc0;  pB11 = B2 + (n0 + 128 + r1) * KPRE + cc1;
  }

  #define STG_A0(kt, b) { gload16(pA00 + (kt)*64, &lA[b][0][c0*8]); gload16(pA01 + (kt)*64, &lA[b][0][c1*8]); }
  #define STG_A1(kt, b) { gload16(pA10 + (kt)*64, &lA[b][1][c0*8]); gload16(pA11 + (kt)*64, &lA[b][1][c1*8]); }
  #define STG_B0(kt, b) { gload16(pB00 + (kt)*64, &lB[b][0][c0*8]); gload16(pB01 + (kt)*64, &lB[b][0][c1*8]); }
  #define STG_B1(kt, b) { gload16(pB10 + (kt)*64, &lB[b][1][c0*8]); gload16(pB11 + (kt)*64, &lB[b][1][c1*8]); }

  int lm = lane & 15;
  int colS0 = ((lane >> 4) * 8) ^ ((lane & 7) << 3);
  int colS1 = (32 + (lane >> 4) * 8) ^ ((lane & 7) << 3);
  int arow[4], brow[2];
  #pragma unroll
  for (int i = 0; i < 4; ++i) arow[i] = (wr * 64 + i * 16 + lm) * 64;
  #pragma unroll
  for (int j = 0; j < 2; ++j) brow[j] = (wc * 32 + j * 16 + lm) * 64;

  bf16x8 aF[4][2], bFh[2][2][2];
  f32x4 acc[2][4][4] = {};

  #define RD_A(qm, b) { _Pragma("unroll") for (int i = 0; i < 4; ++i) {        \
      aF[i][0] = *(const bf16x8*)&lA[b][qm][arow[i] + colS0];                  \
      aF[i][1] = *(const bf16x8*)&lA[b][qm][arow[i] + colS1]; } }
  #define RD_B(h, b) { _Pragma("unroll") for (int j = 0; j < 2; ++j) {         \
      bFh[h][j][0] = *(const bf16x8*)&lB[b][h][brow[j] + colS0];               \
      bFh[h][j][1] = *(const bf16x8*)&lB[b][h][brow[j] + colS1]; } }
  #define MM(qm, qn) { __builtin_amdgcn_s_setprio(1);                          \
      _Pragma("unroll") for (int i = 0; i < 4; ++i)                            \
      _Pragma("unroll") for (int j = 0; j < 2; ++j) {                          \
        acc[qm][i][(qn)*2+j] = __builtin_amdgcn_mfma_f32_16x16x32_bf16(        \
            aF[i][0], bFh[qn][j][0], acc[qm][i][(qn)*2+j], 0, 0, 0);           \
        acc[qm][i][(qn)*2+j] = __builtin_amdgcn_mfma_f32_16x16x32_bf16(        \
            aF[i][1], bFh[qn][j][1], acc[qm][i][(qn)*2+j], 0, 0, 0); }         \
      __builtin_amdgcn_s_setprio(0); }

  STG_A0(0, 0); STG_B0(0, 0); STG_B1(0, 0); STG_A1(0, 0);

  const int nk = KPRE / 64;   // 48
  for (int kt = 0; kt < nk; ++kt) {
    int buf = kt & 1, nbuf = buf ^ 1;
    int ktn = (kt + 1 < nk) ? kt + 1 : kt;
    // P0: needs A0,B0 of kt (oldest 4 loads)
    asm volatile("s_waitcnt vmcnt(4)\n\ts_barrier" ::: "memory");
    RD_A(0, buf); RD_B(0, buf);
    STG_A0(ktn, nbuf);
    MM(0, 0);
    asm volatile("s_barrier" ::: "memory");
    // P1: needs B1 of kt
    asm volatile("s_waitcnt vmcnt(4)\n\ts_barrier" ::: "memory");
    RD_B(1, buf);
    STG_B0(ktn, nbuf);
    MM(0, 1);
    asm volatile("s_barrier" ::: "memory");
    // P2: needs A1 of kt
    asm volatile("s_waitcnt vmcnt(4)\n\ts_barrier" ::: "memory");
    RD_A(1, buf);
    STG_B1(ktn, nbuf);
    MM(1, 0);
    asm volatile("s_barrier" ::: "memory");
    // P3: all fragments already in registers
    STG_A1(ktn, nbuf);
    MM(1, 1);
    asm volatile("s_barrier" ::: "memory");
  }
  #undef STG_A0
  #undef STG_A1
  #undef STG_B0
  #undef STG_B1
  #undef RD_A
  #undef RD_B
  #undef MM

  #pragma unroll
  for (int qm = 0; qm < 2; ++qm)
    #pragma unroll
    for (int i = 0; i < 4; ++i)
      #pragma unroll
      for (int qn = 0; qn < 2; ++qn)
        #pragma unroll
        for (int j = 0; j < 2; ++j)
          #pragma unroll
          for (int q = 0; q < 4; ++q) {
            long m = m0 + qm * 128 + wr * 64 + i * 16 + (lane >> 4) * 4 + q;
            long n = n0 + qn * 128 + wc * 32 + j * 16 + lm;
            if (m >= Mrows) continue;
            float v = acc[qm][i][qn * 2 + j][q];
            if (n < N_RES) {
              ip[m * N_RES + n] = (_Float16)v;
            } else {
              gates[m * 12288 + (n - N_RES)] = (_Float16)(1.f / (1.f + __expf(-v)));
            }
          }
}

// ---------------- per-step GEMM: res = prev_bf16 @ WresBT^T + fused epilogue ----
// BM=64 x BN=32, 256 blocks, 512 threads. BK=256 (16 K-tiles), 3-buffer
// depth-2 counted pipeline (vmcnt(6)), dual accumulator, epilogue operands
// prefetched before the K-loop (oldest in the vmcnt queue -> ledger safe).
__global__ __launch_bounds__(512) void k_step(
    const short* __restrict__ Abf,      // state bf16 (read buf)  [128][4096]
    const short* __restrict__ Bt,       // Wres^T bf16 [4096][4096]
    const _Float16* __restrict__ ip,    // + tloc*128*4096
    const _Float16* __restrict__ gates, // + tloc*128*12288
    float* __restrict__ sF,             // state fp32 [128][4096]
    short* __restrict__ sBw,            // state bf16 (write buf)
    float* __restrict__ out) {          // d_out + t*128*4608
  __shared__ short lA[3][64 * 256];     // 3 x 32 KiB
  __shared__ short lB[3][32 * 256];     // 3 x 16 KiB  (total 144 KiB)
  int tid = threadIdx.x, lane = tid & 63, wid = tid >> 6;   // 8 waves
  int wm = wid >> 1, wn = wid & 1;      // wave tile: 16x16

  // XCD-aware mapping: blockIdx%8 = XCD; n-slice pinned per XCD.
  int b = blockIdx.x;                   // 0..255
  int slot = b >> 3;                    // 0..31
  int n_tile = (b & 7) * 16 + (slot & 15);
  int m_half = slot >> 4;
  int n0 = n_tile * 32;
  int m0 = m_half * 64;

  // staging: A 64x256 shorts = 2048 16B-chunks (4/thread), B 32x256 = 1024 (2/thread)
  // chunk c: row=c>>5, src colchunk=(c&31)^(row&7); dest linear c*16B.
  const short* pA[4];
  const short* pB[2];
  #pragma unroll
  for (int i = 0; i < 4; ++i) {
    int c = i * 512 + tid;
    pA[i] = Abf + (size_t)(m0 + (c >> 5)) * N_RES + (((c & 31) ^ ((c >> 5) & 7)) * 8);
  }
  #pragma unroll
  for (int i = 0; i < 2; ++i) {
    int c = i * 512 + tid;
    pB[i] = Bt + (size_t)(n0 + (c >> 5)) * N_RES + (((c & 31) ^ ((c >> 5) & 7)) * 8);
  }

  #define STAGE(kt, bi) { int k0s = (kt) * 256;                                \
    _Pragma("unroll") for (int i = 0; i < 4; ++i)                              \
      gload16(pA[i] + k0s, &lA[bi][(i * 512 + tid) * 8]);                      \
    _Pragma("unroll") for (int i = 0; i < 2; ++i)                              \
      gload16(pB[i] + k0s, &lB[bi][(i * 512 + tid) * 8]); }

  #define COMPUTE(bi)                                                          \
    { _Pragma("unroll")                                                        \
      for (int kk = 0; kk < 256; kk += 64) {                                   \
        int cS0 = (kk + (lane >> 4) * 8) ^ ((lane & 7) << 3);                  \
        int cS1 = (kk + 32 + (lane >> 4) * 8) ^ ((lane & 7) << 3);             \
        bf16x8 aF0 = *(const bf16x8*)&lA[bi][(wm * 16 + (lane & 15)) * 256 + cS0]; \
        bf16x8 bF0 = *(const bf16x8*)&lB[bi][(wn * 16 + (lane & 15)) * 256 + cS0]; \
        bf16x8 aF1 = *(const bf16x8*)&lA[bi][(wm * 16 + (lane & 15)) * 256 + cS1]; \
        bf16x8 bF1 = *(const bf16x8*)&lB[bi][(wn * 16 + (lane & 15)) * 256 + cS1]; \
        acc0 = __builtin_amdgcn_mfma_f32_16x16x32_bf16(aF0, bF0, acc0, 0, 0, 0);   \
        acc1 = __builtin_amdgcn_mfma_f32_16x16x32_bf16(aF1, bF1, acc1, 0, 0, 0);   \
      } }

  // epilogue operand prefetch (issued FIRST -> oldest in vmcnt queue)
  int mq = m0 + wm * 16 + (lane >> 4) * 4;
  int nn = n0 + wn * 16 + (lane & 15);
  float ipv[4], igv[4], fgv[4], ogv[4], prv[4];
  #pragma unroll
  for (int q = 0; q < 4; ++q) {
    ipv[q] = (float)ip[(size_t)(mq + q) * N_RES + nn];
    const _Float16* grow = gates + (size_t)(mq + q) * 12288 + nn;
    igv[q] = (float)grow[0];
    fgv[q] = (float)grow[4096];
    ogv[q] = (float)grow[8192];
    prv[q] = sF[(size_t)(mq + q) * N_RES + nn];
  }
  __builtin_amdgcn_sched_barrier(0);

  f32x4 acc0 = {}, acc1 = {};
  STAGE(0, 0);
  __builtin_amdgcn_sched_barrier(0);
  STAGE(1, 1);
  __builtin_amdgcn_sched_barrier(0);

  int bi = 0, sb = 2;
  for (int kt = 0; kt < 15; ++kt) {
    // tile kt's 6 loads are the oldest still outstanding -> drain to 6
    asm volatile("s_waitcnt vmcnt(6)" ::: "memory");
    __builtin_amdgcn_s_barrier();
    if (kt < 14) STAGE(kt + 2, sb);
    COMPUTE(bi);
    ++bi; if (bi == 3) bi = 0;
    ++sb; if (sb == 3) sb = 0;
  }
  asm volatile("s_waitcnt vmcnt(0)" ::: "memory");
  __builtin_amdgcn_s_barrier();
  COMPUTE(bi);                          // tile 15
  #undef STAGE
  #undef COMPUTE

  #pragma unroll
  for (int q = 0; q < 4; ++q) {
    float res = acc0[q] + acc1[q];
    float s = 0.9f * (fgv[q] * prv[q]) + 0.1f * tanhf(igv[q] * (ipv[q] + res));
    s = ogv[q] * s;
    if (s > 0.5f) s -= 0.5f;
    out[(size_t)(mq + q) * MAXD + nn] = s;
    sF[(size_t)(mq + q) * N_RES + nn] = s;
    sBw[(size_t)(mq + q) * N_RES + nn] = f2bf(s);
  }
}

extern "C" void kernel_launch(void* const* d_in, const int* in_sizes, int n_in,
                              void* d_out, int out_size, void* d_ws, size_t ws_size,
                              hipStream_t stream) {
  const float* x      = (const float*)d_in[0];
  const float* state0 = (const float*)d_in[1];
  const float* W_res  = (const float*)d_in[2];
  const float* W_in   = (const float*)d_in[3];
  const float* W_gate = (const float*)d_in[4];
  float* out = (float*)d_out;
  char* ws = (char*)d_ws;

  size_t off = 0;
  short* WresBT = (short*)(ws + off); off += (size_t)N_RES * N_RES * 2;       // 33.6 MB
  short* B2     = (short*)(ws + off); off += (size_t)16384 * KPRE * 2;        // 100.7 MB
  float* sF     = (float*)(ws + off); off += (size_t)B_SZ * N_RES * 4;        // 2 MB
  short* sB0    = (short*)(ws + off); off += (size_t)B_SZ * N_RES * 2;        // 1 MB
  short* sB1    = (short*)(ws + off); off += (size_t)B_SZ * N_RES * 2;        // 1 MB
  size_t fixed = off;
  size_t per = (size_t)B_SZ * KPRE * 2 + (size_t)B_SZ * N_RES * 2 + (size_t)B_SZ * 12288 * 2;

  int Tc = T_STEPS;
  while (Tc > 1 && fixed + (size_t)Tc * per > ws_size) Tc >>= 1;

  short*     A2  = (short*)(ws + fixed);
  _Float16*  ipb = (_Float16*)(ws + fixed + (size_t)Tc * B_SZ * KPRE * 2);
  _Float16*  gtb = (_Float16*)(ws + fixed + (size_t)Tc * B_SZ * KPRE * 2
                               + (size_t)Tc * B_SZ * N_RES * 2);

  k_zero_pad<<<T_STEPS * B_SZ, 128, 0, stream>>>(out);
  k_init_state<<<(B_SZ * N_RES) / 256, 256, 0, stream>>>(state0, sF, sB0);
  k_wres_t<<<dim3(64, 64), 256, 0, stream>>>(W_res, WresBT);
  k_build_b2<<<16384, 256, 0, stream>>>(W_in, W_gate, B2);

  for (int t0 = 0; t0 < T_STEPS; t0 += Tc) {
    k_build_a2<<<Tc * B_SZ, 256, 0, stream>>>(x, A2, t0);
    int Mrows = Tc * B_SZ;
    int mtiles = (Mrows + 255) / 256;
    k_gemm_pre<<<mtiles * 64, 512, 0, stream>>>(A2, B2, ipb, gtb, Mrows);
    for (int tl = 0; tl < Tc; ++tl) {
      int t = t0 + tl;
      const short* Ar = (t & 1) ? sB1 : sB0;
      short*       Aw = (t & 1) ? sB0 : sB1;
      k_step<<<256, 512, 0, stream>>>(
          Ar, WresBT,
          ipb + (size_t)tl * B_SZ * N_RES,
          gtb + (size_t)tl * B_SZ * 12288,
          sF, Aw,
          out + (size_t)t * B_SZ * MAXD);
    }
  }
}

// Round 9
// 3228.050 us; speedup vs baseline: 5.8478x; 1.2563x over previous
//
#include <hip/hip_runtime.h>
#include <hip/hip_bf16.h>
#include <hip/hip_fp16.h>

#define N_RES   4096
#define MAXD    4608
#define IN_DIM  1024
#define T_STEPS 128
#define B_SZ    128

typedef __attribute__((ext_vector_type(8))) short bf16x8;
typedef __attribute__((ext_vector_type(8))) _Float16 f16x8;
typedef __attribute__((ext_vector_type(4))) float f32x4;

__device__ __forceinline__ short f2bf(float x) {
  union { float f; unsigned u; } v; v.f = x;
  unsigned r = v.u + 0x7fffu + ((v.u >> 16) & 1u);
  return (short)(r >> 16);
}
__device__ __forceinline__ short f2h(float x) {
  union { _Float16 h; short s; } u; u.h = (_Float16)x; return u.s;
}

__device__ __forceinline__ void gload16(const void* g, void* l) {
  __builtin_amdgcn_global_load_lds(
      (const __attribute__((address_space(1))) void*)g,
      (__attribute__((address_space(3))) void*)l,
      16, 0, 0);
}

// ---------------- zero ONLY the padding columns [4096,4608) ----------------
__global__ void k_zero_pad(float* __restrict__ out) {
  int row = blockIdx.x;            // 16384 rows (T*B)
  int t = threadIdx.x;             // 128 threads * float4 = 512 cols
  *(float4*)(out + (size_t)row * MAXD + N_RES + t * 4) = float4{0.f, 0.f, 0.f, 0.f};
}

// ---------------- init state from state0 ----------------
__global__ void k_init_state(const float* __restrict__ s0,
                             float* __restrict__ sF, short* __restrict__ sB) {
  int i = blockIdx.x * 256 + threadIdx.x;   // 128*4096 total
  int m = i >> 12, n = i & 4095;
  float v = s0[m * MAXD + n];
  sF[i] = v;
  sB[i] = f2bf(v);
}

// ---------------- transpose W_res -> bf16 [n][k] ----------------
__global__ void k_wres_t(const float* __restrict__ W, short* __restrict__ bt) {
  __shared__ float tile[64][65];
  int k0 = blockIdx.y * 64, n0 = blockIdx.x * 64;
  int tx = threadIdx.x & 63, ty = threadIdx.x >> 6;   // 256 thr
  #pragma unroll
  for (int r = 0; r < 64; r += 4)
    tile[r + ty][tx] = W[(long)(k0 + r + ty) * N_RES + n0 + tx];
  __syncthreads();
  #pragma unroll
  for (int r = 0; r < 64; r += 4)
    bt[(long)(n0 + r + ty) * N_RES + k0 + tx] = f2bf(tile[tx][r + ty]);
}

// ---------------- build B2 = fp16 rows of [W_in;W_gate]  [16384][1024] ---------
__global__ void k_build_b2(const float* __restrict__ Win,
                           const float* __restrict__ Wg, short* __restrict__ B2) {
  int r = blockIdx.x;   // 16384 rows
  const float* src = (r < N_RES) ? (Win + (long)r * IN_DIM)
                                 : (Wg + (long)(r - N_RES) * IN_DIM);
  short* dst = B2 + (long)r * IN_DIM;
  for (int c = threadIdx.x; c < IN_DIM; c += 256)
    dst[c] = f2h(src[c]);
}

// ---------------- build A2 = fp16 x chunk  [Tc*128][1024] ----------------
__global__ void k_build_a2(const float* __restrict__ x, short* __restrict__ A2, int t0) {
  int r = blockIdx.x;   // Tc*128 rows
  const float* src = x + (long)(t0 * B_SZ + r) * IN_DIM;
  short* dst = A2 + (long)r * IN_DIM;
  for (int c = threadIdx.x; c < IN_DIM; c += 256)
    dst[c] = f2h(src[c]);
}

// ---------------- precompute GEMM: C = A2 @ B2^T  (256x256 8-phase, fp16 K=1024) --
// BM=BN=256, BK=64, 512 thr (8 waves 2Mx4N), per-wave 128x64 out.
// LDS: 2buf x 2half x 128x64 for A and B = 128 KiB. XOR-swizzled (both sides).
// B fragments for both halves held in registers; counted vmcnt(4) per phase.
__global__ __launch_bounds__(512, 2) void k_gemm_pre(
    const short* __restrict__ A2, const short* __restrict__ B2,
    _Float16* __restrict__ ip, _Float16* __restrict__ gates, int Mrows) {
  __shared__ short lA[2][2][128 * 64];
  __shared__ short lB[2][2][128 * 64];
  int tid = threadIdx.x, lane = tid & 63, wid = tid >> 6;
  int wr = wid >> 2, wc = wid & 3;

  // bijective XCD swizzle (m204), mt-major chunks per XCD
  int nwg = gridDim.x, orig = blockIdx.x;
  int qx = nwg >> 3, rx = nwg & 7, xcd = orig & 7;
  int wgid = (xcd < rx ? xcd * (qx + 1) : rx * (qx + 1) + (xcd - rx) * qx) + (orig >> 3);
  int mt = wgid >> 6, nt = wgid & 63;
  long m0 = (long)mt * 256, n0 = (long)nt * 256;
  long mclamp = Mrows - 1;

  int c0 = tid, c1 = 512 + tid;
  int r0 = c0 >> 3, r1 = c1 >> 3;
  int cc0 = ((c0 & 7) ^ (r0 & 7)) * 8, cc1 = ((c1 & 7) ^ (r1 & 7)) * 8;

  const short *pA00, *pA01, *pA10, *pA11, *pB00, *pB01, *pB10, *pB11;
  {
    long a00 = m0 + r0;       if (a00 > mclamp) a00 = mclamp;
    long a01 = m0 + r1;       if (a01 > mclamp) a01 = mclamp;
    long a10 = m0 + 128 + r0; if (a10 > mclamp) a10 = mclamp;
    long a11 = m0 + 128 + r1; if (a11 > mclamp) a11 = mclamp;
    pA00 = A2 + a00 * IN_DIM + cc0;  pA01 = A2 + a01 * IN_DIM + cc1;
    pA10 = A2 + a10 * IN_DIM + cc0;  pA11 = A2 + a11 * IN_DIM + cc1;
    pB00 = B2 + (n0 + r0) * IN_DIM + cc0;        pB01 = B2 + (n0 + r1) * IN_DIM + cc1;
    pB10 = B2 + (n0 + 128 + r0) * IN_DIM + cc0;  pB11 = B2 + (n0 + 128 + r1) * IN_DIM + cc1;
  }

  #define STG_A0(kt, b) { gload16(pA00 + (kt)*64, &lA[b][0][c0*8]); gload16(pA01 + (kt)*64, &lA[b][0][c1*8]); }
  #define STG_A1(kt, b) { gload16(pA10 + (kt)*64, &lA[b][1][c0*8]); gload16(pA11 + (kt)*64, &lA[b][1][c1*8]); }
  #define STG_B0(kt, b) { gload16(pB00 + (kt)*64, &lB[b][0][c0*8]); gload16(pB01 + (kt)*64, &lB[b][0][c1*8]); }
  #define STG_B1(kt, b) { gload16(pB10 + (kt)*64, &lB[b][1][c0*8]); gload16(pB11 + (kt)*64, &lB[b][1][c1*8]); }

  int lm = lane & 15;
  int colS0 = ((lane >> 4) * 8) ^ ((lane & 7) << 3);
  int colS1 = (32 + (lane >> 4) * 8) ^ ((lane & 7) << 3);
  int arow[4], brow[2];
  #pragma unroll
  for (int i = 0; i < 4; ++i) arow[i] = (wr * 64 + i * 16 + lm) * 64;
  #pragma unroll
  for (int j = 0; j < 2; ++j) brow[j] = (wc * 32 + j * 16 + lm) * 64;

  f16x8 aF[4][2], bFh[2][2][2];
  f32x4 acc[2][4][4] = {};

  #define RD_A(qm, b) { _Pragma("unroll") for (int i = 0; i < 4; ++i) {        \
      aF[i][0] = *(const f16x8*)&lA[b][qm][arow[i] + colS0];                   \
      aF[i][1] = *(const f16x8*)&lA[b][qm][arow[i] + colS1]; } }
  #define RD_B(h, b) { _Pragma("unroll") for (int j = 0; j < 2; ++j) {         \
      bFh[h][j][0] = *(const f16x8*)&lB[b][h][brow[j] + colS0];                \
      bFh[h][j][1] = *(const f16x8*)&lB[b][h][brow[j] + colS1]; } }
  #define MM(qm, qn) { __builtin_amdgcn_s_setprio(1);                          \
      _Pragma("unroll") for (int i = 0; i < 4; ++i)                            \
      _Pragma("unroll") for (int j = 0; j < 2; ++j) {                          \
        acc[qm][i][(qn)*2+j] = __builtin_amdgcn_mfma_f32_16x16x32_f16(         \
            aF[i][0], bFh[qn][j][0], acc[qm][i][(qn)*2+j], 0, 0, 0);           \
        acc[qm][i][(qn)*2+j] = __builtin_amdgcn_mfma_f32_16x16x32_f16(         \
            aF[i][1], bFh[qn][j][1], acc[qm][i][(qn)*2+j], 0, 0, 0); }         \
      __builtin_amdgcn_s_setprio(0); }

  STG_A0(0, 0); STG_B0(0, 0); STG_B1(0, 0); STG_A1(0, 0);

  const int nk = IN_DIM / 64;   // 16
  for (int kt = 0; kt < nk; ++kt) {
    int buf = kt & 1, nbuf = buf ^ 1;
    int ktn = (kt + 1 < nk) ? kt + 1 : kt;
    // P0: needs A0,B0 of kt (oldest 4 loads)
    asm volatile("s_waitcnt vmcnt(4)\n\ts_barrier" ::: "memory");
    RD_A(0, buf); RD_B(0, buf);
    STG_A0(ktn, nbuf);
    MM(0, 0);
    asm volatile("s_barrier" ::: "memory");
    // P1: needs B1 of kt
    asm volatile("s_waitcnt vmcnt(4)\n\ts_barrier" ::: "memory");
    RD_B(1, buf);
    STG_B0(ktn, nbuf);
    MM(0, 1);
    asm volatile("s_barrier" ::: "memory");
    // P2: needs A1 of kt
    asm volatile("s_waitcnt vmcnt(4)\n\ts_barrier" ::: "memory");
    RD_A(1, buf);
    STG_B1(ktn, nbuf);
    MM(1, 0);
    asm volatile("s_barrier" ::: "memory");
    // P3: all fragments already in registers
    STG_A1(ktn, nbuf);
    MM(1, 1);
    asm volatile("s_barrier" ::: "memory");
  }
  #undef STG_A0
  #undef STG_A1
  #undef STG_B0
  #undef STG_B1
  #undef RD_A
  #undef RD_B
  #undef MM

  #pragma unroll
  for (int qm = 0; qm < 2; ++qm)
    #pragma unroll
    for (int i = 0; i < 4; ++i)
      #pragma unroll
      for (int qn = 0; qn < 2; ++qn)
        #pragma unroll
        for (int j = 0; j < 2; ++j)
          #pragma unroll
          for (int q = 0; q < 4; ++q) {
            long m = m0 + qm * 128 + wr * 64 + i * 16 + (lane >> 4) * 4 + q;
            long n = n0 + qn * 128 + wc * 32 + j * 16 + lm;
            if (m >= Mrows) continue;
            float v = acc[qm][i][qn * 2 + j][q];
            if (n < N_RES) {
              ip[m * N_RES + n] = (_Float16)v;
            } else {
              gates[m * 12288 + (n - N_RES)] = (_Float16)(1.f / (1.f + __expf(-v)));
            }
          }
}

// ---------------- per-step GEMM: res = prev_bf16 @ WresBT^T + fused epilogue ----
// BM=32 x BN=64 (A-broadcast halved vs 64x32), 256 blocks, 512 threads.
// BK=256 (16 K-tiles), 3-buffer depth-2 counted pipeline (vmcnt(6)),
// dual accumulator, epilogue operands prefetched before the K-loop.
__global__ __launch_bounds__(512) void k_step(
    const short* __restrict__ Abf,      // state bf16 (read buf)  [128][4096]
    const short* __restrict__ Bt,       // Wres^T bf16 [4096][4096]
    const _Float16* __restrict__ ip,    // + tloc*128*4096
    const _Float16* __restrict__ gates, // + tloc*128*12288
    float* __restrict__ sF,             // state fp32 [128][4096]
    short* __restrict__ sBw,            // state bf16 (write buf)
    float* __restrict__ out) {          // d_out + t*128*4608
  __shared__ short lA[3][32 * 256];     // 3 x 16 KiB
  __shared__ short lB[3][64 * 256];     // 3 x 32 KiB  (total 144 KiB)
  int tid = threadIdx.x, lane = tid & 63, wid = tid >> 6;   // 8 waves
  int wm = wid >> 2, wn = wid & 3;      // wave tile 16x16: 2 m x 4 n

  // XCD-aware mapping: blockIdx%8 = XCD; 8 n-tiles (B-slice 4 MB) per XCD L2.
  int b = blockIdx.x;                   // 0..255
  int slot = b >> 3;                    // 0..31
  int n_tile = (b & 7) * 8 + (slot & 7);   // 0..63
  int m_q = slot >> 3;                  // 0..3
  int n0 = n_tile * 64;
  int m0 = m_q * 32;

  // staging: A 32x256 shorts = 1024 16B-chunks (2/thread), B 64x256 = 2048 (4/thread)
  // chunk c: row=c>>5, src colchunk=(c&31)^(row&7); dest linear c*16B.
  const short* pA[2];
  const short* pB[4];
  #pragma unroll
  for (int i = 0; i < 2; ++i) {
    int c = i * 512 + tid;
    pA[i] = Abf + (size_t)(m0 + (c >> 5)) * N_RES + (((c & 31) ^ ((c >> 5) & 7)) * 8);
  }
  #pragma unroll
  for (int i = 0; i < 4; ++i) {
    int c = i * 512 + tid;
    pB[i] = Bt + (size_t)(n0 + (c >> 5)) * N_RES + (((c & 31) ^ ((c >> 5) & 7)) * 8);
  }

  #define STAGE(kt, bi) { int k0s = (kt) * 256;                                \
    _Pragma("unroll") for (int i = 0; i < 2; ++i)                              \
      gload16(pA[i] + k0s, &lA[bi][(i * 512 + tid) * 8]);                      \
    _Pragma("unroll") for (int i = 0; i < 4; ++i)                              \
      gload16(pB[i] + k0s, &lB[bi][(i * 512 + tid) * 8]); }

  #define COMPUTE(bi)                                                          \
    { _Pragma("unroll")                                                        \
      for (int kk = 0; kk < 256; kk += 64) {                                   \
        int cS0 = (kk + (lane >> 4) * 8) ^ ((lane & 7) << 3);                  \
        int cS1 = (kk + 32 + (lane >> 4) * 8) ^ ((lane & 7) << 3);             \
        bf16x8 aF0 = *(const bf16x8*)&lA[bi][(wm * 16 + (lane & 15)) * 256 + cS0]; \
        bf16x8 bF0 = *(const bf16x8*)&lB[bi][(wn * 16 + (lane & 15)) * 256 + cS0]; \
        bf16x8 aF1 = *(const bf16x8*)&lA[bi][(wm * 16 + (lane & 15)) * 256 + cS1]; \
        bf16x8 bF1 = *(const bf16x8*)&lB[bi][(wn * 16 + (lane & 15)) * 256 + cS1]; \
        acc0 = __builtin_amdgcn_mfma_f32_16x16x32_bf16(aF0, bF0, acc0, 0, 0, 0);   \
        acc1 = __builtin_amdgcn_mfma_f32_16x16x32_bf16(aF1, bF1, acc1, 0, 0, 0);   \
      } }

  // epilogue operand prefetch (issued FIRST -> oldest in vmcnt queue)
  int mq = m0 + wm * 16 + (lane >> 4) * 4;
  int nn = n0 + wn * 16 + (lane & 15);
  float ipv[4], igv[4], fgv[4], ogv[4], prv[4];
  #pragma unroll
  for (int q = 0; q < 4; ++q) {
    ipv[q] = (float)ip[(size_t)(mq + q) * N_RES + nn];
    const _Float16* grow = gates + (size_t)(mq + q) * 12288 + nn;
    igv[q] = (float)grow[0];
    fgv[q] = (float)grow[4096];
    ogv[q] = (float)grow[8192];
    prv[q] = sF[(size_t)(mq + q) * N_RES + nn];
  }
  __builtin_amdgcn_sched_barrier(0);

  f32x4 acc0 = {}, acc1 = {};
  STAGE(0, 0);
  __builtin_amdgcn_sched_barrier(0);
  STAGE(1, 1);
  __builtin_amdgcn_sched_barrier(0);

  int bi = 0, sb = 2;
  for (int kt = 0; kt < 15; ++kt) {
    // tile kt's 6 loads are the oldest still outstanding -> drain to 6
    asm volatile("s_waitcnt vmcnt(6)" ::: "memory");
    __builtin_amdgcn_s_barrier();
    if (kt < 14) STAGE(kt + 2, sb);
    COMPUTE(bi);
    ++bi; if (bi == 3) bi = 0;
    ++sb; if (sb == 3) sb = 0;
  }
  asm volatile("s_waitcnt vmcnt(0)" ::: "memory");
  __builtin_amdgcn_s_barrier();
  COMPUTE(bi);                          // tile 15
  #undef STAGE
  #undef COMPUTE

  #pragma unroll
  for (int q = 0; q < 4; ++q) {
    float res = acc0[q] + acc1[q];
    float s = 0.9f * (fgv[q] * prv[q]) + 0.1f * tanhf(igv[q] * (ipv[q] + res));
    s = ogv[q] * s;
    if (s > 0.5f) s -= 0.5f;
    out[(size_t)(mq + q) * MAXD + nn] = s;
    sF[(size_t)(mq + q) * N_RES + nn] = s;
    sBw[(size_t)(mq + q) * N_RES + nn] = f2bf(s);
  }
}

extern "C" void kernel_launch(void* const* d_in, const int* in_sizes, int n_in,
                              void* d_out, int out_size, void* d_ws, size_t ws_size,
                              hipStream_t stream) {
  const float* x      = (const float*)d_in[0];
  const float* state0 = (const float*)d_in[1];
  const float* W_res  = (const float*)d_in[2];
  const float* W_in   = (const float*)d_in[3];
  const float* W_gate = (const float*)d_in[4];
  float* out = (float*)d_out;
  char* ws = (char*)d_ws;

  size_t off = 0;
  short* WresBT = (short*)(ws + off); off += (size_t)N_RES * N_RES * 2;       // 33.6 MB
  short* B2     = (short*)(ws + off); off += (size_t)16384 * IN_DIM * 2;      // 33.6 MB
  float* sF     = (float*)(ws + off); off += (size_t)B_SZ * N_RES * 4;        // 2 MB
  short* sB0    = (short*)(ws + off); off += (size_t)B_SZ * N_RES * 2;        // 1 MB
  short* sB1    = (short*)(ws + off); off += (size_t)B_SZ * N_RES * 2;        // 1 MB
  size_t fixed = off;
  size_t per = (size_t)B_SZ * IN_DIM * 2 + (size_t)B_SZ * N_RES * 2 + (size_t)B_SZ * 12288 * 2;

  int Tc = T_STEPS;
  while (Tc > 1 && fixed + (size_t)Tc * per > ws_size) Tc >>= 1;

  short*     A2  = (short*)(ws + fixed);
  _Float16*  ipb = (_Float16*)(ws + fixed + (size_t)Tc * B_SZ * IN_DIM * 2);
  _Float16*  gtb = (_Float16*)(ws + fixed + (size_t)Tc * B_SZ * IN_DIM * 2
                               + (size_t)Tc * B_SZ * N_RES * 2);

  k_zero_pad<<<T_STEPS * B_SZ, 128, 0, stream>>>(out);
  k_init_state<<<(B_SZ * N_RES) / 256, 256, 0, stream>>>(state0, sF, sB0);
  k_wres_t<<<dim3(64, 64), 256, 0, stream>>>(W_res, WresBT);
  k_build_b2<<<16384, 256, 0, stream>>>(W_in, W_gate, B2);

  for (int t0 = 0; t0 < T_STEPS; t0 += Tc) {
    k_build_a2<<<Tc * B_SZ, 256, 0, stream>>>(x, A2, t0);
    int Mrows = Tc * B_SZ;
    int mtiles = (Mrows + 255) / 256;
    k_gemm_pre<<<mtiles * 64, 512, 0, stream>>>(A2, B2, ipb, gtb, Mrows);
    for (int tl = 0; tl < Tc; ++tl) {
      int t = t0 + tl;
      const short* Ar = (t & 1) ? sB1 : sB0;
      short*       Aw = (t & 1) ? sB0 : sB1;
      k_step<<<256, 512, 0, stream>>>(
          Ar, WresBT,
          ipb + (size_t)tl * B_SZ * N_RES,
          gtb + (size_t)tl * B_SZ * 12288,
          sF, Aw,
          out + (size_t)t * B_SZ * MAXD);
    }
  }
}

// Round 10
// 2795.462 us; speedup vs baseline: 6.7527x; 1.1547x over previous
//
#include <hip/hip_runtime.h>
#include <hip/hip_bf16.h>
#include <hip/hip_fp16.h>

#define N_RES   4096
#define MAXD    4608
#define IN_DIM  1024
#define T_STEPS 128
#define B_SZ    128

typedef __attribute__((ext_vector_type(8))) short bf16x8;
typedef __attribute__((ext_vector_type(8))) _Float16 f16x8;
typedef __attribute__((ext_vector_type(4))) float f32x4;

__device__ __forceinline__ short f2bf(float x) {
  union { float f; unsigned u; } v; v.f = x;
  unsigned r = v.u + 0x7fffu + ((v.u >> 16) & 1u);
  return (short)(r >> 16);
}
__device__ __forceinline__ short f2h(float x) {
  union { _Float16 h; short s; } u; u.h = (_Float16)x; return u.s;
}
__device__ __forceinline__ float h2f(short s) {
  union { _Float16 h; short s; } u; u.s = s; return (float)u.h;
}

__device__ __forceinline__ void gload16(const void* g, void* l) {
  __builtin_amdgcn_global_load_lds(
      (const __attribute__((address_space(1))) void*)g,
      (__attribute__((address_space(3))) void*)l,
      16, 0, 0);
}

// ---------------- zero ONLY the padding columns [4096,4608) ----------------
__global__ void k_zero_pad(float* __restrict__ out) {
  int row = blockIdx.x;            // 16384 rows (T*B)
  int t = threadIdx.x;             // 128 threads * float4 = 512 cols
  *(float4*)(out + (size_t)row * MAXD + N_RES + t * 4) = float4{0.f, 0.f, 0.f, 0.f};
}

// ---------------- init state from state0 ----------------
__global__ void k_init_state(const float* __restrict__ s0,
                             float* __restrict__ sF, short* __restrict__ sB) {
  int i = blockIdx.x * 256 + threadIdx.x;   // 128*4096 total
  int m = i >> 12, n = i & 4095;
  float v = s0[m * MAXD + n];
  sF[i] = v;
  sB[i] = f2bf(v);
}

// ---------------- transpose W_res -> bf16 [n][k] ----------------
__global__ void k_wres_t(const float* __restrict__ W, short* __restrict__ bt) {
  __shared__ float tile[64][65];
  int k0 = blockIdx.y * 64, n0 = blockIdx.x * 64;
  int tx = threadIdx.x & 63, ty = threadIdx.x >> 6;   // 256 thr
  #pragma unroll
  for (int r = 0; r < 64; r += 4)
    tile[r + ty][tx] = W[(long)(k0 + r + ty) * N_RES + n0 + tx];
  __syncthreads();
  #pragma unroll
  for (int r = 0; r < 64; r += 4)
    bt[(long)(n0 + r + ty) * N_RES + k0 + tx] = f2bf(tile[tx][r + ty]);
}

// ---------------- build B2 = fp16 rows of [W_in;W_gate]  [16384][1024] ---------
__global__ void k_build_b2(const float* __restrict__ Win,
                           const float* __restrict__ Wg, short* __restrict__ B2) {
  int r = blockIdx.x;   // 16384 rows
  const float* src = (r < N_RES) ? (Win + (long)r * IN_DIM)
                                 : (Wg + (long)(r - N_RES) * IN_DIM);
  short* dst = B2 + (long)r * IN_DIM;
  for (int c = threadIdx.x; c < IN_DIM; c += 256)
    dst[c] = f2h(src[c]);
}

// ---------------- build A2 = fp16 x chunk  [Tc*128][1024] ----------------
__global__ void k_build_a2(const float* __restrict__ x, short* __restrict__ A2, int t0) {
  int r = blockIdx.x;   // Tc*128 rows
  const float* src = x + (long)(t0 * B_SZ + r) * IN_DIM;
  short* dst = A2 + (long)r * IN_DIM;
  for (int c = threadIdx.x; c < IN_DIM; c += 256)
    dst[c] = f2h(src[c]);
}

// ---------------- precompute GEMM: C = A2 @ B2^T  (256x256 8-phase, fp16 K=1024) --
// BM=BN=256, BK=64, 512 thr. Per-XCD nt-slab (8 nt, B-slab 4MB L2-resident) with
// 4mt x 8nt concurrent squares (32 blocks = 1 XCD's CUs).
__global__ __launch_bounds__(512, 2) void k_gemm_pre(
    const short* __restrict__ A2, const short* __restrict__ B2,
    _Float16* __restrict__ ip, _Float16* __restrict__ gates, int Mrows) {
  __shared__ short lA[2][2][128 * 64];
  __shared__ short lB[2][2][128 * 64];
  int tid = threadIdx.x, lane = tid & 63, wid = tid >> 6;
  int wr = wid >> 2, wc = wid & 3;

  int nwg = gridDim.x, orig = blockIdx.x;
  int mtiles = nwg >> 6;
  int mt, nt;
  if ((mtiles & 3) == 0) {
    // per-XCD nt-slab + square traversal
    int xcd = orig & 7, idx = orig >> 3;
    int w = idx & 31, sq = idx >> 5;
    nt = xcd * 8 + (w & 7);
    mt = sq * 4 + (w >> 3);
  } else {
    // fallback: bijective m204 swizzle
    int qx = nwg >> 3, rx = nwg & 7, xcd = orig & 7;
    int wgid = (xcd < rx ? xcd * (qx + 1) : rx * (qx + 1) + (xcd - rx) * qx) + (orig >> 3);
    mt = wgid >> 6; nt = wgid & 63;
  }
  long m0 = (long)mt * 256, n0 = (long)nt * 256;
  long mclamp = Mrows - 1;

  int c0 = tid, c1 = 512 + tid;
  int r0 = c0 >> 3, r1 = c1 >> 3;
  int cc0 = ((c0 & 7) ^ (r0 & 7)) * 8, cc1 = ((c1 & 7) ^ (r1 & 7)) * 8;

  const short *pA00, *pA01, *pA10, *pA11, *pB00, *pB01, *pB10, *pB11;
  {
    long a00 = m0 + r0;       if (a00 > mclamp) a00 = mclamp;
    long a01 = m0 + r1;       if (a01 > mclamp) a01 = mclamp;
    long a10 = m0 + 128 + r0; if (a10 > mclamp) a10 = mclamp;
    long a11 = m0 + 128 + r1; if (a11 > mclamp) a11 = mclamp;
    pA00 = A2 + a00 * IN_DIM + cc0;  pA01 = A2 + a01 * IN_DIM + cc1;
    pA10 = A2 + a10 * IN_DIM + cc0;  pA11 = A2 + a11 * IN_DIM + cc1;
    pB00 = B2 + (n0 + r0) * IN_DIM + cc0;        pB01 = B2 + (n0 + r1) * IN_DIM + cc1;
    pB10 = B2 + (n0 + 128 + r0) * IN_DIM + cc0;  pB11 = B2 + (n0 + 128 + r1) * IN_DIM + cc1;
  }

  #define STG_A0(kt, b) { gload16(pA00 + (kt)*64, &lA[b][0][c0*8]); gload16(pA01 + (kt)*64, &lA[b][0][c1*8]); }
  #define STG_A1(kt, b) { gload16(pA10 + (kt)*64, &lA[b][1][c0*8]); gload16(pA11 + (kt)*64, &lA[b][1][c1*8]); }
  #define STG_B0(kt, b) { gload16(pB00 + (kt)*64, &lB[b][0][c0*8]); gload16(pB01 + (kt)*64, &lB[b][0][c1*8]); }
  #define STG_B1(kt, b) { gload16(pB10 + (kt)*64, &lB[b][1][c0*8]); gload16(pB11 + (kt)*64, &lB[b][1][c1*8]); }

  int lm = lane & 15;
  int colS0 = ((lane >> 4) * 8) ^ ((lane & 7) << 3);
  int colS1 = (32 + (lane >> 4) * 8) ^ ((lane & 7) << 3);
  int arow[4], brow[2];
  #pragma unroll
  for (int i = 0; i < 4; ++i) arow[i] = (wr * 64 + i * 16 + lm) * 64;
  #pragma unroll
  for (int j = 0; j < 2; ++j) brow[j] = (wc * 32 + j * 16 + lm) * 64;

  f16x8 aF[4][2], bFh[2][2][2];
  f32x4 acc[2][4][4] = {};

  #define RD_A(qm, b) { _Pragma("unroll") for (int i = 0; i < 4; ++i) {        \
      aF[i][0] = *(const f16x8*)&lA[b][qm][arow[i] + colS0];                   \
      aF[i][1] = *(const f16x8*)&lA[b][qm][arow[i] + colS1]; } }
  #define RD_B(h, b) { _Pragma("unroll") for (int j = 0; j < 2; ++j) {         \
      bFh[h][j][0] = *(const f16x8*)&lB[b][h][brow[j] + colS0];                \
      bFh[h][j][1] = *(const f16x8*)&lB[b][h][brow[j] + colS1]; } }
  #define MM(qm, qn) { __builtin_amdgcn_s_setprio(1);                          \
      _Pragma("unroll") for (int i = 0; i < 4; ++i)                            \
      _Pragma("unroll") for (int j = 0; j < 2; ++j) {                          \
        acc[qm][i][(qn)*2+j] = __builtin_amdgcn_mfma_f32_16x16x32_f16(         \
            aF[i][0], bFh[qn][j][0], acc[qm][i][(qn)*2+j], 0, 0, 0);           \
        acc[qm][i][(qn)*2+j] = __builtin_amdgcn_mfma_f32_16x16x32_f16(         \
            aF[i][1], bFh[qn][j][1], acc[qm][i][(qn)*2+j], 0, 0, 0); }         \
      __builtin_amdgcn_s_setprio(0); }

  STG_A0(0, 0); STG_B0(0, 0); STG_B1(0, 0); STG_A1(0, 0);

  const int nk = IN_DIM / 64;   // 16
  for (int kt = 0; kt < nk; ++kt) {
    int buf = kt & 1, nbuf = buf ^ 1;
    int ktn = (kt + 1 < nk) ? kt + 1 : kt;
    asm volatile("s_waitcnt vmcnt(4)\n\ts_barrier" ::: "memory");
    RD_A(0, buf); RD_B(0, buf);
    STG_A0(ktn, nbuf);
    MM(0, 0);
    asm volatile("s_barrier" ::: "memory");
    asm volatile("s_waitcnt vmcnt(4)\n\ts_barrier" ::: "memory");
    RD_B(1, buf);
    STG_B0(ktn, nbuf);
    MM(0, 1);
    asm volatile("s_barrier" ::: "memory");
    asm volatile("s_waitcnt vmcnt(4)\n\ts_barrier" ::: "memory");
    RD_A(1, buf);
    STG_B1(ktn, nbuf);
    MM(1, 0);
    asm volatile("s_barrier" ::: "memory");
    STG_A1(ktn, nbuf);
    MM(1, 1);
    asm volatile("s_barrier" ::: "memory");
  }
  #undef STG_A0
  #undef STG_A1
  #undef STG_B0
  #undef STG_B1
  #undef RD_A
  #undef RD_B
  #undef MM

  #pragma unroll
  for (int qm = 0; qm < 2; ++qm)
    #pragma unroll
    for (int i = 0; i < 4; ++i)
      #pragma unroll
      for (int qn = 0; qn < 2; ++qn)
        #pragma unroll
        for (int j = 0; j < 2; ++j)
          #pragma unroll
          for (int q = 0; q < 4; ++q) {
            long m = m0 + qm * 128 + wr * 64 + i * 16 + (lane >> 4) * 4 + q;
            long n = n0 + qn * 128 + wc * 32 + j * 16 + lm;
            if (m >= Mrows) continue;
            float v = acc[qm][i][qn * 2 + j][q];
            if (n < N_RES) {
              ip[m * N_RES + n] = (_Float16)v;
            } else {
              gates[m * 12288 + (n - N_RES)] = (_Float16)(1.f / (1.f + __expf(-v)));
            }
          }
}

// ---------------- per-step GEMM (K-split): partial[kc] = prev @ Wres^T[kc-slice] --
// 256 blocks = 2 m_h x 32 n_t x 4 kc. BM=64, BN=128, Kc=1024, BK=128 (8 tiles).
// 3-buffer depth-2 counted pipeline (vmcnt(6)). Per-block bytes 384KB (was 768).
__global__ __launch_bounds__(512) void k_step_gemm(
    const short* __restrict__ Abf,      // state bf16 (read buf) [128][4096]
    const short* __restrict__ Bt,       // Wres^T bf16 [4096][4096]
    float* __restrict__ part) {         // [4][128][4096] f32
  __shared__ short lA[3][64 * 128];     // 3 x 16 KiB
  __shared__ short lB[3][128 * 128];    // 3 x 32 KiB (total 144 KiB)
  int tid = threadIdx.x, lane = tid & 63, wid = tid >> 6;   // 8 waves
  int wm = wid >> 2, wn = wid & 3;      // wave tile 32x32 (2m x 4n waves)

  // XCD mapping: xcd = b&7; per XCD: 4 n_t x 4 kc x 2 m_h (B WS 4MB -> L2)
  int b = blockIdx.x;
  int xcd = b & 7, i2 = b >> 3;
  int m_h = i2 & 1, kc = (i2 >> 1) & 3, n_tl = i2 >> 3;   // 0..3
  int n_t = xcd * 4 + n_tl;             // 0..31
  int m0 = m_h * 64, n0 = n_t * 128, kb = kc * 1024;

  // staging: A 64x128 = 1024 16B-chunks (2/thr), B 128x128 = 2048 (4/thr)
  const short* pA[2];
  const short* pB[4];
  #pragma unroll
  for (int i = 0; i < 2; ++i) {
    int c = i * 512 + tid, row = c >> 4;
    pA[i] = Abf + (size_t)(m0 + row) * N_RES + kb + (((c & 15) ^ (row & 7)) * 8);
  }
  #pragma unroll
  for (int i = 0; i < 4; ++i) {
    int c = i * 512 + tid, row = c >> 4;
    pB[i] = Bt + (size_t)(n0 + row) * N_RES + kb + (((c & 15) ^ (row & 7)) * 8);
  }

  #define STAGE(kt, bi) { int k0s = (kt) * 128;                                \
    _Pragma("unroll") for (int i = 0; i < 2; ++i)                              \
      gload16(pA[i] + k0s, &lA[bi][(i * 512 + tid) * 8]);                      \
    _Pragma("unroll") for (int i = 0; i < 4; ++i)                              \
      gload16(pB[i] + k0s, &lB[bi][(i * 512 + tid) * 8]); }

  f32x4 acc[2][2] = {};

  #define COMPUTE(bi)                                                          \
    { _Pragma("unroll")                                                        \
      for (int kk = 0; kk < 128; kk += 32) {                                   \
        int colS = (kk + (lane >> 4) * 8) ^ ((lane & 7) << 3);                 \
        bf16x8 aF0 = *(const bf16x8*)&lA[bi][(wm * 32 + (lane & 15)) * 128 + colS];      \
        bf16x8 aF1 = *(const bf16x8*)&lA[bi][(wm * 32 + 16 + (lane & 15)) * 128 + colS]; \
        bf16x8 bF0 = *(const bf16x8*)&lB[bi][(wn * 32 + (lane & 15)) * 128 + colS];      \
        bf16x8 bF1 = *(const bf16x8*)&lB[bi][(wn * 32 + 16 + (lane & 15)) * 128 + colS]; \
        acc[0][0] = __builtin_amdgcn_mfma_f32_16x16x32_bf16(aF0, bF0, acc[0][0], 0, 0, 0); \
        acc[0][1] = __builtin_amdgcn_mfma_f32_16x16x32_bf16(aF0, bF1, acc[0][1], 0, 0, 0); \
        acc[1][0] = __builtin_amdgcn_mfma_f32_16x16x32_bf16(aF1, bF0, acc[1][0], 0, 0, 0); \
        acc[1][1] = __builtin_amdgcn_mfma_f32_16x16x32_bf16(aF1, bF1, acc[1][1], 0, 0, 0); \
      } }

  STAGE(0, 0);
  STAGE(1, 1);                          // 12 loads in flight

  int bi = 0, sb = 2;
  for (int kt = 0; kt < 7; ++kt) {
    asm volatile("s_waitcnt vmcnt(6)" ::: "memory");
    __builtin_amdgcn_s_barrier();
    if (kt < 6) STAGE(kt + 2, sb);
    COMPUTE(bi);
    ++bi; if (bi == 3) bi = 0;
    ++sb; if (sb == 3) sb = 0;
  }
  asm volatile("s_waitcnt vmcnt(0)" ::: "memory");
  __builtin_amdgcn_s_barrier();
  COMPUTE(bi);                          // tile 7
  #undef STAGE
  #undef COMPUTE

  float* dst = part + (size_t)kc * (B_SZ * N_RES);
  #pragma unroll
  for (int i = 0; i < 2; ++i)
    #pragma unroll
    for (int j = 0; j < 2; ++j)
      #pragma unroll
      for (int q = 0; q < 4; ++q) {
        int m = m0 + wm * 32 + i * 16 + (lane >> 4) * 4 + q;
        int n = n0 + wn * 32 + j * 16 + (lane & 15);
        dst[(size_t)m * N_RES + n] = acc[i][j][q];
      }
}

// ---------------- per-step reduce + gate epilogue ----------------
// 512 blocks x 256 thr, 4 elems/thread (float4). Sums 4 K-partials, applies
// gates/tanh/spike, writes out + fp32 state + bf16 state.
__global__ void k_step_red(
    const float* __restrict__ part,     // [4][128][4096]
    const _Float16* __restrict__ ip,    // [128][4096]
    const _Float16* __restrict__ gt,    // [128][12288]
    float* __restrict__ sF,             // fp32 state
    short* __restrict__ sBw,            // bf16 state (write buf)
    float* __restrict__ out) {          // d_out + t*128*4608
  int e = (blockIdx.x * 256 + threadIdx.x) * 4;
  int m = e >> 12, n = e & 4095;
  float4 p0 = *(const float4*)(part + e);
  float4 p1 = *(const float4*)(part + (1 << 19) + e);
  float4 p2 = *(const float4*)(part + (2 << 19) + e);
  float4 p3 = *(const float4*)(part + (3 << 19) + e);
  short4 ipr = *(const short4*)((const short*)ip + e);
  const short* g = (const short*)gt + (size_t)m * 12288 + n;
  short4 igr = *(const short4*)g;
  short4 fgr = *(const short4*)(g + 4096);
  short4 ogr = *(const short4*)(g + 8192);
  float4 pr = *(const float4*)(sF + e);

  float res[4] = { p0.x + p1.x + p2.x + p3.x, p0.y + p1.y + p2.y + p3.y,
                   p0.z + p1.z + p2.z + p3.z, p0.w + p1.w + p2.w + p3.w };
  float prv[4] = { pr.x, pr.y, pr.z, pr.w };
  short ipa[4] = { ipr.x, ipr.y, ipr.z, ipr.w };
  short iga[4] = { igr.x, igr.y, igr.z, igr.w };
  short fga[4] = { fgr.x, fgr.y, fgr.z, fgr.w };
  short oga[4] = { ogr.x, ogr.y, ogr.z, ogr.w };

  float so[4];
  short sb[4];
  #pragma unroll
  for (int q = 0; q < 4; ++q) {
    float s = 0.9f * (h2f(fga[q]) * prv[q])
            + 0.1f * tanhf(h2f(iga[q]) * (h2f(ipa[q]) + res[q]));
    s = h2f(oga[q]) * s;
    if (s > 0.5f) s -= 0.5f;
    so[q] = s;
    sb[q] = f2bf(s);
  }
  *(float4*)(out + (size_t)m * MAXD + n) = float4{so[0], so[1], so[2], so[3]};
  *(float4*)(sF + e) = float4{so[0], so[1], so[2], so[3]};
  *(short4*)(sBw + e) = short4{sb[0], sb[1], sb[2], sb[3]};
}

extern "C" void kernel_launch(void* const* d_in, const int* in_sizes, int n_in,
                              void* d_out, int out_size, void* d_ws, size_t ws_size,
                              hipStream_t stream) {
  const float* x      = (const float*)d_in[0];
  const float* state0 = (const float*)d_in[1];
  const float* W_res  = (const float*)d_in[2];
  const float* W_in   = (const float*)d_in[3];
  const float* W_gate = (const float*)d_in[4];
  float* out = (float*)d_out;
  char* ws = (char*)d_ws;

  size_t off = 0;
  short* WresBT = (short*)(ws + off); off += (size_t)N_RES * N_RES * 2;       // 33.6 MB
  short* B2     = (short*)(ws + off); off += (size_t)16384 * IN_DIM * 2;      // 33.6 MB
  float* sF     = (float*)(ws + off); off += (size_t)B_SZ * N_RES * 4;        // 2 MB
  short* sB0    = (short*)(ws + off); off += (size_t)B_SZ * N_RES * 2;        // 1 MB
  short* sB1    = (short*)(ws + off); off += (size_t)B_SZ * N_RES * 2;        // 1 MB
  float* part   = (float*)(ws + off); off += (size_t)4 * B_SZ * N_RES * 4;    // 8 MB
  size_t fixed = off;
  size_t per = (size_t)B_SZ * IN_DIM * 2 + (size_t)B_SZ * N_RES * 2 + (size_t)B_SZ * 12288 * 2;

  int Tc = T_STEPS;
  while (Tc > 1 && fixed + (size_t)Tc * per > ws_size) Tc >>= 1;

  short*     A2  = (short*)(ws + fixed);
  _Float16*  ipb = (_Float16*)(ws + fixed + (size_t)Tc * B_SZ * IN_DIM * 2);
  _Float16*  gtb = (_Float16*)(ws + fixed + (size_t)Tc * B_SZ * IN_DIM * 2
                               + (size_t)Tc * B_SZ * N_RES * 2);

  k_zero_pad<<<T_STEPS * B_SZ, 128, 0, stream>>>(out);
  k_init_state<<<(B_SZ * N_RES) / 256, 256, 0, stream>>>(state0, sF, sB0);
  k_wres_t<<<dim3(64, 64), 256, 0, stream>>>(W_res, WresBT);
  k_build_b2<<<16384, 256, 0, stream>>>(W_in, W_gate, B2);

  for (int t0 = 0; t0 < T_STEPS; t0 += Tc) {
    k_build_a2<<<Tc * B_SZ, 256, 0, stream>>>(x, A2, t0);
    int Mrows = Tc * B_SZ;
    int mtiles = (Mrows + 255) / 256;
    k_gemm_pre<<<mtiles * 64, 512, 0, stream>>>(A2, B2, ipb, gtb, Mrows);
    for (int tl = 0; tl < Tc; ++tl) {
      int t = t0 + tl;
      const short* Ar = (t & 1) ? sB1 : sB0;
      short*       Aw = (t & 1) ? sB0 : sB1;
      k_step_gemm<<<256, 512, 0, stream>>>(Ar, WresBT, part);
      k_step_red<<<512, 256, 0, stream>>>(
          part,
          ipb + (size_t)tl * B_SZ * N_RES,
          gtb + (size_t)tl * B_SZ * 12288,
          sF, Aw,
          out + (size_t)t * B_SZ * MAXD);
    }
  }
}